// Round 7
// baseline (234.342 us; speedup 1.0000x reference)
//
#include <hip/hip_runtime.h>
#include <math.h>

#define DM 256
#define LSEQ 2048
#define BATCH 8
#define NLAYER 8
#define EMAX 192
#define LN_EPS 1e-5f
#define BM 64
#define ROWS (BATCH * LSEQ)

// LDS layout (bytes)
#define HT_STRIDE 1040              // 260 f32 per row: breaks bank alignment
#define AB_OFF   66560              // 64*1040  -> Ah [64 rows][512 B, XOR-swizzled]
#define AL_OFF   (AB_OFF + 32768)   // Al
#define RED_OFF  (AL_OFF + 32768)   // red [64 rows][4 waves][2] f32
#define SMEM_SZ  (RED_OFF + 2048)   // 134144 B -> 1 block/CU

typedef float f32x4 __attribute__((ext_vector_type(4)));
typedef short bf16x8 __attribute__((ext_vector_type(8)));
typedef unsigned short u16;
typedef unsigned short u16x4 __attribute__((ext_vector_type(4)));
typedef unsigned short u16x8 __attribute__((ext_vector_type(8)));

union V8 { u16x8 u; bf16x8 b; };

__device__ __forceinline__ float gelu_exact(float v) {
    return 0.5f * v * (1.f + erff(v * 0.70710678118654752f));
}

// split fp32 -> bf16 hi (truncated, exact-subtractable) + bf16 lo (RNE of remainder)
__device__ __forceinline__ void split2(float g, u16& hi, u16& lo) {
    unsigned u = __float_as_uint(g);
    hi = (u16)(u >> 16);
    float fh = __uint_as_float(u & 0xFFFF0000u);
    float r = g - fh;
    unsigned v = __float_as_uint(r);
    v = v + 0x7FFFu + ((v >> 16) & 1u);
    lo = (u16)(v >> 16);
}

// ---------------- pre-split pW into MFMA-fragment-packed bf16 hi/lo ----------------
// packed[((cg*8+ks)*64+lane)*8 + j] = pW[col][k], col=(cg>>2)*64+(cg&3)*16+fr,
// k=ks*32+fq*8+j, lane=fq*16+fr.  (verified in r5)
__global__ void k_prepW(const float* __restrict__ pW, u16* __restrict__ pWh,
                        u16* __restrict__ pWl) {
    int i = blockIdx.x * blockDim.x + threadIdx.x;
    int e = i * 8;
    int l = e >> 16;
    int r = e & 65535;
    int cg = r >> 12;
    int ks = (r >> 9) & 7;
    int lane = (r >> 3) & 63;
    int fq = lane >> 4, fr = lane & 15;
    int col = (cg >> 2) * 64 + (cg & 3) * 16 + fr;
    int k = ks * 32 + fq * 8;
    const float* src = pW + l * 65536 + col * 256 + k;
    float4 w0 = *(const float4*)src;
    float4 w1 = *(const float4*)(src + 4);
    float vv[8] = {w0.x, w0.y, w0.z, w0.w, w1.x, w1.y, w1.z, w1.w};
    u16 sh[8], sl[8];
#pragma unroll
    for (int j = 0; j < 8; ++j) split2(vv[j], sh[j], sl[j]);
    u16x8 vh = {sh[0], sh[1], sh[2], sh[3], sh[4], sh[5], sh[6], sh[7]};
    u16x8 vl = {sl[0], sl[1], sl[2], sl[3], sl[4], sl[5], sl[6], sl[7]};
    *(u16x8*)&pWh[e] = vh;
    *(u16x8*)&pWl[e] = vl;
}

// ---------------- prep0: logA/CB all layers, P[0], zero P[1..7] + pooled ----------------
__global__ void k_prep0(const float* __restrict__ x, const float* __restrict__ inW,
                        const float* __restrict__ inb, const float* __restrict__ Ap,
                        const float* __restrict__ Bp, const float* __restrict__ Cp,
                        float* __restrict__ P_all, float* __restrict__ logA_all,
                        float* __restrict__ CB_all, float* __restrict__ pooled) {
    int b = blockIdx.x;
    int c = threadIdx.x;
    float A0 = 1.f / (1.f + expf(-Ap[c]));
    float iw = inW[c], ib = inb[c];
    const float* xb = x + b * LSEQ;
    float pw = 1.f, acc = 0.f;
    for (int t = 0; t <= EMAX; ++t) {
        acc += (xb[t] * iw + ib) * pw;
        pw *= A0;
    }
    P_all[b * DM + c] = acc;
    for (int l = 1; l < NLAYER; ++l) P_all[l * BATCH * DM + b * DM + c] = 0.f;
    for (int e = 0; e < 4; ++e) pooled[e * BATCH * DM + b * DM + c] = 0.f;
    if (b == 0) {
        for (int l = 0; l < NLAYER; ++l) {
            float Al = 1.f / (1.f + expf(-Ap[l * DM + c]));
            logA_all[l * DM + c] = logf(Al);
            CB_all[l * DM + c]   = Bp[l * DM + c] * Cp[l * DM + c];
        }
    }
}

// ---------------- persistent-tile fused kernel: 64 rows through all 8 layers ----------------
// 512 thr = 8 waves (wm=wv>>2 row-half, wn=wv&3 col-slice). h tile lives in LDS (f32),
// residual in registers. Launched twice: blocks 0..27/batch (producers, no tail), then
// blocks 28..31/batch (tail consumers; P[l] complete by then).
__global__ __launch_bounds__(512, 2) void k_fused(
    int bpb, int blkoff,
    const float* __restrict__ x, const float* __restrict__ inW,
    const float* __restrict__ inb,
    const u16* __restrict__ pWh, const u16* __restrict__ pWl,
    const float* __restrict__ Dp_all, const float* __restrict__ pb_all,
    const float* __restrict__ lng_all, const float* __restrict__ lnb_all,
    const float* __restrict__ logA_all, const float* __restrict__ CB_all,
    float* __restrict__ P_all, float* __restrict__ pooled)
{
    __shared__ __align__(16) char smem[SMEM_SZ];

    int tid  = threadIdx.x;
    int lane = tid & 63;
    int wv   = tid >> 6;
    int wm   = wv >> 2;
    int wn   = wv & 3;
    int fr   = lane & 15;
    int fq   = lane >> 4;

    int batch = blockIdx.x / bpb;
    int blk   = blockIdx.x % bpb + blkoff;
    int brow  = batch * LSEQ + blk * BM;
    int b     = batch;

    // stage map
    int srow = tid >> 3;                 // 0..63
    int gr_s = brow + srow;
    int t_s  = gr_s & (LSEQ - 1);
    int u_s  = (LSEQ - 1) - t_s;
    bool tail_s = (u_s <= EMAX);
    float uf = (float)u_s;
    float xv = x[gr_s];

    float hreg[2][4][4];                 // residual h for owned (m,n,r)

    for (int l = 0; l < NLAYER; ++l) {
        const float* Dp  = Dp_all   + l * DM;
        const float* la  = logA_all + l * DM;
        const float* cbp = CB_all   + l * DM;
        const float* Pl  = P_all + (size_t)l * BATCH * DM + b * DM;

        // ---- stage: g = split(gelu(D*h + tail)) into Ah/Al; l==0 also fills hT ----
#pragma unroll
        for (int i = 0; i < 4; ++i) {
            int u  = (tid & 7) + 8 * i;      // 32B chunk 0..31
            int kk = u * 8;
            int hby = srow * HT_STRIDE + u * 32;
            float hv[8];
            if (l == 0) {
                float4 w0 = *(const float4*)&inW[kk], w1 = *(const float4*)&inW[kk + 4];
                float4 b0 = *(const float4*)&inb[kk], b1 = *(const float4*)&inb[kk + 4];
                hv[0] = fmaf(xv, w0.x, b0.x); hv[1] = fmaf(xv, w0.y, b0.y);
                hv[2] = fmaf(xv, w0.z, b0.z); hv[3] = fmaf(xv, w0.w, b0.w);
                hv[4] = fmaf(xv, w1.x, b1.x); hv[5] = fmaf(xv, w1.y, b1.y);
                hv[6] = fmaf(xv, w1.z, b1.z); hv[7] = fmaf(xv, w1.w, b1.w);
                float4 o0 = {hv[0], hv[1], hv[2], hv[3]};
                float4 o1 = {hv[4], hv[5], hv[6], hv[7]};
                *(float4*)(smem + hby) = o0;
                *(float4*)(smem + hby + 16) = o1;
            } else {
                float4 h0 = *(const float4*)(smem + hby);
                float4 h1 = *(const float4*)(smem + hby + 16);
                hv[0] = h0.x; hv[1] = h0.y; hv[2] = h0.z; hv[3] = h0.w;
                hv[4] = h1.x; hv[5] = h1.y; hv[6] = h1.z; hv[7] = h1.w;
            }
            float4 d0 = *(const float4*)&Dp[kk];
            float4 d1 = *(const float4*)&Dp[kk + 4];
            float vv[8];
            vv[0] = hv[0] * d0.x; vv[1] = hv[1] * d0.y;
            vv[2] = hv[2] * d0.z; vv[3] = hv[3] * d0.w;
            vv[4] = hv[4] * d1.x; vv[5] = hv[5] * d1.y;
            vv[6] = hv[6] * d1.z; vv[7] = hv[7] * d1.w;
            if (tail_s) {
                float4 la0 = *(const float4*)&la[kk],  la1 = *(const float4*)&la[kk + 4];
                float4 cb0 = *(const float4*)&cbp[kk], cb1 = *(const float4*)&cbp[kk + 4];
                float4 P0  = *(const float4*)&Pl[kk],  P1  = *(const float4*)&Pl[kk + 4];
                vv[0] += cb0.x * expf(uf * la0.x) * P0.x;
                vv[1] += cb0.y * expf(uf * la0.y) * P0.y;
                vv[2] += cb0.z * expf(uf * la0.z) * P0.z;
                vv[3] += cb0.w * expf(uf * la0.w) * P0.w;
                vv[4] += cb1.x * expf(uf * la1.x) * P1.x;
                vv[5] += cb1.y * expf(uf * la1.y) * P1.y;
                vv[6] += cb1.z * expf(uf * la1.z) * P1.z;
                vv[7] += cb1.w * expf(uf * la1.w) * P1.w;
            }
            u16 sh[8], sl[8];
#pragma unroll
            for (int j = 0; j < 8; ++j) split2(gelu_exact(vv[j]), sh[j], sl[j]);
            u16x8 vh = {sh[0], sh[1], sh[2], sh[3], sh[4], sh[5], sh[6], sh[7]};
            u16x8 vl = {sl[0], sl[1], sl[2], sl[3], sl[4], sl[5], sl[6], sl[7]};
            int aby = srow * 512 + ((u ^ (srow & 7)) << 4);
            *(u16x8*)(smem + AB_OFF + aby) = vh;
            *(u16x8*)(smem + AL_OFF + aby) = vl;
        }
        __syncthreads();   // bar A: Ah/Al (and hT at l==0) ready

        // ---- MFMA: A from LDS, B from packed global (L2-hot) ----
        f32x4 acc[2][4];
#pragma unroll
        for (int m = 0; m < 2; ++m)
#pragma unroll
            for (int n = 0; n < 4; ++n) acc[m][n] = (f32x4){0.f, 0.f, 0.f, 0.f};

        const u16* bhp = pWh + (size_t)l * 65536 + wn * 16384 + lane * 8;
        const u16* blp = pWl + (size_t)l * 65536 + wn * 16384 + lane * 8;

#pragma unroll
        for (int ks = 0; ks < 8; ++ks) {
            V8 ah[2], al[2];
#pragma unroll
            for (int m = 0; m < 2; ++m) {
                int row = wm * 32 + m * 16 + fr;
                int aby = row * 512 + (((ks * 4 + fq) ^ (row & 7)) << 4);
                ah[m].u = *(const u16x8*)(smem + AB_OFF + aby);
                al[m].u = *(const u16x8*)(smem + AL_OFF + aby);
            }
            V8 bh[4], bl[4];
#pragma unroll
            for (int n = 0; n < 4; ++n) {
                bh[n].u = *(const u16x8*)&bhp[(n * 8 + ks) * 512];
                bl[n].u = *(const u16x8*)&blp[(n * 8 + ks) * 512];
            }
#pragma unroll
            for (int m = 0; m < 2; ++m)
#pragma unroll
                for (int n = 0; n < 4; ++n) {
                    acc[m][n] = __builtin_amdgcn_mfma_f32_16x16x32_bf16(ah[m].b, bh[n].b, acc[m][n], 0, 0, 0);
                    acc[m][n] = __builtin_amdgcn_mfma_f32_16x16x32_bf16(ah[m].b, bl[n].b, acc[m][n], 0, 0, 0);
                    acc[m][n] = __builtin_amdgcn_mfma_f32_16x16x32_bf16(al[m].b, bh[n].b, acc[m][n], 0, 0, 0);
                }
        }

        // ---- epilogue p1: y = h + out2 + pb; row sums; cross-wave reduce ----
        if (l == 0) {
#pragma unroll
            for (int m = 0; m < 2; ++m)
#pragma unroll
                for (int n = 0; n < 4; ++n)
#pragma unroll
                    for (int r = 0; r < 4; ++r) {
                        int row = wm * 32 + m * 16 + fq * 4 + r;
                        int col = wn * 64 + n * 16 + fr;
                        hreg[m][n][r] = *(const float*)(smem + row * HT_STRIDE + col * 4);
                    }
        }
        float pbv[4], lgv[4], lbv[4];
#pragma unroll
        for (int n = 0; n < 4; ++n) {
            int col = wn * 64 + n * 16 + fr;
            pbv[n] = pb_all[l * DM + col];
            lgv[n] = lng_all[l * DM + col];
            lbv[n] = lnb_all[l * DM + col];
        }
        float s[2][4], ss[2][4];
#pragma unroll
        for (int m = 0; m < 2; ++m)
#pragma unroll
            for (int r = 0; r < 4; ++r) {
                float sy = 0.f, sy2 = 0.f;
#pragma unroll
                for (int n = 0; n < 4; ++n) {
                    float y = hreg[m][n][r] + acc[m][n][r] + pbv[n];
                    acc[m][n][r] = y;
                    sy += y; sy2 += y * y;
                }
                s[m][r] = sy; ss[m][r] = sy2;
            }
#pragma unroll
        for (int m = 0; m < 2; ++m)
#pragma unroll
            for (int r = 0; r < 4; ++r)
#pragma unroll
                for (int msk = 1; msk < 16; msk <<= 1) {
                    s[m][r]  += __shfl_xor(s[m][r],  msk);
                    ss[m][r] += __shfl_xor(ss[m][r], msk);
                }
        if (fr == 0) {
#pragma unroll
            for (int m = 0; m < 2; ++m)
#pragma unroll
                for (int r = 0; r < 4; ++r) {
                    int row = wm * 32 + m * 16 + fq * 4 + r;
                    *(float*)(smem + RED_OFF + (row * 8 + wn * 2)     * 4) = s[m][r];
                    *(float*)(smem + RED_OFF + (row * 8 + wn * 2 + 1) * 4) = ss[m][r];
                }
        }
        __syncthreads();   // bar B: red ready

        // ---- epilogue p2: LN, write-back, pooled, P_next ----
        float mean[2][4], rstd[2][4];
#pragma unroll
        for (int m = 0; m < 2; ++m)
#pragma unroll
            for (int r = 0; r < 4; ++r) {
                int row = wm * 32 + m * 16 + fq * 4 + r;
                float st = 0.f, sst = 0.f;
#pragma unroll
                for (int w = 0; w < 4; ++w) {
                    st  += *(const float*)(smem + RED_OFF + (row * 8 + w * 2)     * 4);
                    sst += *(const float*)(smem + RED_OFF + (row * 8 + w * 2 + 1) * 4);
                }
                float mu = st * (1.f / 256.f);
                float var = sst * (1.f / 256.f) - mu * mu;
                mean[m][r] = mu;
                rstd[m][r] = rsqrtf(var + LN_EPS);
            }
        int slot = (l == 1) ? 0 : (l == 3) ? 1 : (l == 5) ? 2 : (l == 7) ? 3 : -1;
        bool prod = (l < NLAYER - 1) && (blk <= 3);
        float lanv[4];
        if (prod) {
            const float* lan = logA_all + (l + 1) * DM;
#pragma unroll
            for (int n = 0; n < 4; ++n) lanv[n] = lan[wn * 64 + n * 16 + fr];
        }
        float cs[4] = {0.f, 0.f, 0.f, 0.f};
        float pc[4] = {0.f, 0.f, 0.f, 0.f};
#pragma unroll
        for (int m = 0; m < 2; ++m)
#pragma unroll
            for (int r = 0; r < 4; ++r) {
                int row  = wm * 32 + m * 16 + fq * 4 + r;
                int trow = blk * BM + row;
#pragma unroll
                for (int n = 0; n < 4; ++n) {
                    float o = (acc[m][n][r] - mean[m][r]) * rstd[m][r] * lgv[n] + lbv[n];
                    hreg[m][n][r] = o;
                    int col = wn * 64 + n * 16 + fr;
                    *(float*)(smem + row * HT_STRIDE + col * 4) = o;
                    if (slot >= 0) cs[n] += o;
                    if (prod && trow <= EMAX) pc[n] += o * expf((float)trow * lanv[n]);
                }
            }
        if (slot >= 0) {
#pragma unroll
            for (int n = 0; n < 4; ++n) {
                cs[n] += __shfl_xor(cs[n], 16);
                cs[n] += __shfl_xor(cs[n], 32);
            }
            if (lane < 16) {
#pragma unroll
                for (int n = 0; n < 4; ++n)
                    atomicAdd(&pooled[slot * (BATCH * DM) + b * DM + wn * 64 + n * 16 + lane], cs[n]);
            }
        }
        if (prod) {
#pragma unroll
            for (int n = 0; n < 4; ++n) {
                pc[n] += __shfl_xor(pc[n], 16);
                pc[n] += __shfl_xor(pc[n], 32);
            }
            if (lane < 16) {
#pragma unroll
                for (int n = 0; n < 4; ++n)
                    atomicAdd(&P_all[(size_t)(l + 1) * BATCH * DM + b * DM + wn * 64 + n * 16 + lane], pc[n]);
            }
        }
        __syncthreads();   // bar C: hT/red safe for next layer
    }
}

// ---------------- head ----------------
__global__ void k_head(const float* __restrict__ pooled, const float* __restrict__ hW,
                       const float* __restrict__ hb, float* __restrict__ out) {
    int tid = threadIdx.x;
    if (tid >= 96) return;
    int e = tid / 24;
    int r = tid % 24;
    int b = r / 3;
    int n = r % 3;
    const float* pv = &pooled[e * (BATCH * DM) + b * DM];
    const float* wv = &hW[(e * 3 + n) * DM];
    float acc = 0.f;
    for (int c = 0; c < DM; ++c) acc += pv[c] * wv[c];
    out[e * 24 + b * 3 + n] = acc * (1.f / (float)LSEQ) + hb[e * 3 + n];
}

extern "C" void kernel_launch(void* const* d_in, const int* in_sizes, int n_in,
                              void* d_out, int out_size, void* d_ws, size_t ws_size,
                              hipStream_t stream) {
    const float* x   = (const float*)d_in[0];
    const float* inW = (const float*)d_in[1];
    const float* inb = (const float*)d_in[2];
    const float* Ap  = (const float*)d_in[3];
    const float* Bp  = (const float*)d_in[4];
    const float* Cp  = (const float*)d_in[5];
    const float* Dp  = (const float*)d_in[6];
    const float* pW  = (const float*)d_in[7];
    const float* pb  = (const float*)d_in[8];
    const float* lng = (const float*)d_in[9];
    const float* lnb = (const float*)d_in[10];
    const float* hW  = (const float*)d_in[11];
    const float* hb  = (const float*)d_in[12];
    float* out = (float*)d_out;

    float* ws = (float*)d_ws;
    float* P_all    = ws;                            // 8*8*256 = 16384
    float* logA_all = P_all + NLAYER * BATCH * DM;   // 2048
    float* CB_all   = logA_all + NLAYER * DM;        // 2048
    float* pooled   = CB_all + NLAYER * DM;          // 8192
    u16* pWh        = (u16*)(pooled + 4 * BATCH * DM);   // 524288 u16
    u16* pWl        = pWh + NLAYER * DM * DM;            // 524288 u16

    k_prepW<<<(NLAYER * DM * DM / 8) / 256, 256, 0, stream>>>(pW, pWh, pWl);
    k_prep0<<<BATCH, 256, 0, stream>>>(x, inW, inb, Ap, Bp, Cp,
                                       P_all, logA_all, CB_all, pooled);
    // launch 1: blocks 0..27 per batch (includes all P-producers, no tail rows)
    k_fused<<<BATCH * 28, 512, 0, stream>>>(
        28, 0, x, inW, inb, pWh, pWl, Dp, pb, lng, lnb,
        logA_all, CB_all, P_all, pooled);
    // launch 2: blocks 28..31 per batch (tail consumers; P complete)
    k_fused<<<BATCH * 4, 512, 0, stream>>>(
        4, 28, x, inW, inb, pWh, pWl, Dp, pb, lng, lnb,
        logA_all, CB_all, P_all, pooled);
    k_head<<<1, 128, 0, stream>>>(pooled, hW, hb, out);
}

// Round 8
// 135.919 us; speedup vs baseline: 1.7241x; 1.7241x over previous
//
#include <hip/hip_runtime.h>
#include <math.h>

#define DM 256
#define LSEQ 2048
#define BATCH 8
#define NLAYER 8
#define EMAX 192
#define LN_EPS 1e-5f
#define BM 64
#define ROWS (BATCH * LSEQ)

// LDS layout (bytes)
#define HT_STRIDE 1040              // 260 f32 per row: breaks bank alignment
#define AB_OFF   66560              // 64*1040  -> Ah [64 rows][512 B, XOR-swizzled]
#define AL_OFF   (AB_OFF + 32768)   // Al
#define RED_OFF  (AL_OFF + 32768)   // red [64 rows][4 waves][2] f32 ; doubles as Pbuf during stage
#define SMEM_SZ  (RED_OFF + 2048)   // 134144 B -> 1 block/CU, 256 blocks = 256 CUs

typedef float f32x4 __attribute__((ext_vector_type(4)));
typedef short bf16x8 __attribute__((ext_vector_type(8)));
typedef unsigned short u16;
typedef unsigned short u16x4 __attribute__((ext_vector_type(4)));
typedef unsigned short u16x8 __attribute__((ext_vector_type(8)));

union V8 { u16x8 u; bf16x8 b; };

__device__ __forceinline__ float gelu_exact(float v) {
    return 0.5f * v * (1.f + erff(v * 0.70710678118654752f));
}

// split fp32 -> bf16 hi (truncated, exact-subtractable) + bf16 lo (RNE of remainder)
__device__ __forceinline__ void split2(float g, u16& hi, u16& lo) {
    unsigned u = __float_as_uint(g);
    hi = (u16)(u >> 16);
    float fh = __uint_as_float(u & 0xFFFF0000u);
    float r = g - fh;
    unsigned v = __float_as_uint(r);
    v = v + 0x7FFFu + ((v >> 16) & 1u);
    lo = (u16)(v >> 16);
}

// ---------------- pre-split pW into MFMA-fragment-packed bf16 hi/lo ----------------
// packed[((cg*8+ks)*64+lane)*8 + j] = pW[col][k], col=(cg>>2)*64+(cg&3)*16+fr,
// k=ks*32+fq*8+j, lane=fq*16+fr.  (verified r5/r7)
__global__ void k_prepW(const float* __restrict__ pW, u16* __restrict__ pWh,
                        u16* __restrict__ pWl) {
    int i = blockIdx.x * blockDim.x + threadIdx.x;
    int e = i * 8;
    int l = e >> 16;
    int r = e & 65535;
    int cg = r >> 12;
    int ks = (r >> 9) & 7;
    int lane = (r >> 3) & 63;
    int fq = lane >> 4, fr = lane & 15;
    int col = (cg >> 2) * 64 + (cg & 3) * 16 + fr;
    int k = ks * 32 + fq * 8;
    const float* src = pW + l * 65536 + col * 256 + k;
    float4 w0 = *(const float4*)src;
    float4 w1 = *(const float4*)(src + 4);
    float vv[8] = {w0.x, w0.y, w0.z, w0.w, w1.x, w1.y, w1.z, w1.w};
    u16 sh[8], sl[8];
#pragma unroll
    for (int j = 0; j < 8; ++j) split2(vv[j], sh[j], sl[j]);
    u16x8 vh = {sh[0], sh[1], sh[2], sh[3], sh[4], sh[5], sh[6], sh[7]};
    u16x8 vl = {sl[0], sl[1], sl[2], sl[3], sl[4], sl[5], sl[6], sl[7]};
    *(u16x8*)&pWh[e] = vh;
    *(u16x8*)&pWl[e] = vl;
}

// ---------------- prep0: logA/CB all layers, P[0], zero P[1..7] + pooled + flags ----------------
__global__ void k_prep0(const float* __restrict__ x, const float* __restrict__ inW,
                        const float* __restrict__ inb, const float* __restrict__ Ap,
                        const float* __restrict__ Bp, const float* __restrict__ Cp,
                        float* __restrict__ P_all, float* __restrict__ logA_all,
                        float* __restrict__ CB_all, float* __restrict__ pooled,
                        int* __restrict__ flags) {
    int b = blockIdx.x;
    int c = threadIdx.x;
    float A0 = 1.f / (1.f + expf(-Ap[c]));
    float iw = inW[c], ib = inb[c];
    const float* xb = x + b * LSEQ;
    float pw = 1.f, acc = 0.f;
    for (int t = 0; t <= EMAX; ++t) {
        acc += (xb[t] * iw + ib) * pw;
        pw *= A0;
    }
    P_all[b * DM + c] = acc;
    for (int l = 1; l < NLAYER; ++l) P_all[l * BATCH * DM + b * DM + c] = 0.f;
    for (int e = 0; e < 4; ++e) pooled[e * BATCH * DM + b * DM + c] = 0.f;
    if (b == 0) {
        for (int l = 0; l < NLAYER; ++l) {
            float Al = 1.f / (1.f + expf(-Ap[l * DM + c]));
            logA_all[l * DM + c] = logf(Al);
            CB_all[l * DM + c]   = Bp[l * DM + c] * Cp[l * DM + c];
        }
        if (c < NLAYER * BATCH) flags[c] = 0;
    }
}

// ---------------- persistent-tile fused kernel: 64 rows through all 8 layers ----------------
// Single launch, 256 blocks (1/CU, all co-resident). Producer blocks (blk<=3) release
// flags[l+1][b] after their layer-l epilogue; tail blocks (blk>=28, the only P-consumers)
// spin + snapshot P into LDS via agent-scope atomic loads.
__global__ __launch_bounds__(512, 2) void k_fused(
    const float* __restrict__ x, const float* __restrict__ inW,
    const float* __restrict__ inb,
    const u16* __restrict__ pWh, const u16* __restrict__ pWl,
    const float* __restrict__ Dp_all, const float* __restrict__ pb_all,
    const float* __restrict__ lng_all, const float* __restrict__ lnb_all,
    const float* __restrict__ logA_all, const float* __restrict__ CB_all,
    float* __restrict__ P_all, float* __restrict__ pooled,
    int* __restrict__ flags)
{
    __shared__ __align__(16) char smem[SMEM_SZ];

    int tid  = threadIdx.x;
    int lane = tid & 63;
    int wv   = tid >> 6;
    int wm   = wv >> 2;
    int wn   = wv & 3;
    int fr   = lane & 15;
    int fq   = lane >> 4;

    int b    = blockIdx.x >> 5;
    int blk  = blockIdx.x & 31;
    int brow = b * LSEQ + blk * BM;
    bool isTail = (blk >= 28);      // contains rows with u<=EMAX (t>=1855)
    bool isProd = (blk <= 3);       // contains rows with t<=EMAX

    // stage map
    int srow = tid >> 3;                 // 0..63
    int gr_s = brow + srow;
    int t_s  = gr_s & (LSEQ - 1);
    int u_s  = (LSEQ - 1) - t_s;
    bool tail_s = (u_s <= EMAX);
    float uf = (float)u_s;
    float xv = x[gr_s];

    float hreg[2][4][4];                 // residual h for owned (m,n,r)
    float* Pbuf = (float*)(smem + RED_OFF);   // aliases red area (disjoint in time)

    for (int l = 0; l < NLAYER; ++l) {
        const float* Dp  = Dp_all   + l * DM;
        const float* la  = logA_all + l * DM;
        const float* cbp = CB_all   + l * DM;

        // ---- tail blocks: wait for P[l] complete, snapshot into LDS ----
        if (isTail) {
            if (l >= 1 && tid == 0) {
                while (__hip_atomic_load(&flags[l * BATCH + b], __ATOMIC_ACQUIRE,
                                         __HIP_MEMORY_SCOPE_AGENT) < 4)
                    __builtin_amdgcn_s_sleep(2);
            }
            __syncthreads();
            if (tid < DM)
                Pbuf[tid] = __hip_atomic_load(
                    &P_all[(size_t)l * BATCH * DM + b * DM + tid],
                    __ATOMIC_RELAXED, __HIP_MEMORY_SCOPE_AGENT);
            __syncthreads();
        }

        // ---- stage: g = split(gelu(D*h + tail)) into Ah/Al; l==0 also fills hT ----
#pragma unroll
        for (int i = 0; i < 4; ++i) {
            int u  = (tid & 7) + 8 * i;      // 16B chunk 0..31
            int kk = u * 8;
            int hby = srow * HT_STRIDE + u * 32;
            float hv[8];
            if (l == 0) {
                float4 w0 = *(const float4*)&inW[kk], w1 = *(const float4*)&inW[kk + 4];
                float4 b0 = *(const float4*)&inb[kk], b1 = *(const float4*)&inb[kk + 4];
                hv[0] = fmaf(xv, w0.x, b0.x); hv[1] = fmaf(xv, w0.y, b0.y);
                hv[2] = fmaf(xv, w0.z, b0.z); hv[3] = fmaf(xv, w0.w, b0.w);
                hv[4] = fmaf(xv, w1.x, b1.x); hv[5] = fmaf(xv, w1.y, b1.y);
                hv[6] = fmaf(xv, w1.z, b1.z); hv[7] = fmaf(xv, w1.w, b1.w);
                float4 o0 = {hv[0], hv[1], hv[2], hv[3]};
                float4 o1 = {hv[4], hv[5], hv[6], hv[7]};
                *(float4*)(smem + hby) = o0;
                *(float4*)(smem + hby + 16) = o1;
            } else {
                float4 h0 = *(const float4*)(smem + hby);
                float4 h1 = *(const float4*)(smem + hby + 16);
                hv[0] = h0.x; hv[1] = h0.y; hv[2] = h0.z; hv[3] = h0.w;
                hv[4] = h1.x; hv[5] = h1.y; hv[6] = h1.z; hv[7] = h1.w;
            }
            float4 d0 = *(const float4*)&Dp[kk];
            float4 d1 = *(const float4*)&Dp[kk + 4];
            float vv[8];
            vv[0] = hv[0] * d0.x; vv[1] = hv[1] * d0.y;
            vv[2] = hv[2] * d0.z; vv[3] = hv[3] * d0.w;
            vv[4] = hv[4] * d1.x; vv[5] = hv[5] * d1.y;
            vv[6] = hv[6] * d1.z; vv[7] = hv[7] * d1.w;
            if (tail_s) {
                float4 la0 = *(const float4*)&la[kk],  la1 = *(const float4*)&la[kk + 4];
                float4 cb0 = *(const float4*)&cbp[kk], cb1 = *(const float4*)&cbp[kk + 4];
                float4 P0  = *(const float4*)&Pbuf[kk], P1 = *(const float4*)&Pbuf[kk + 4];
                vv[0] += cb0.x * expf(uf * la0.x) * P0.x;
                vv[1] += cb0.y * expf(uf * la0.y) * P0.y;
                vv[2] += cb0.z * expf(uf * la0.z) * P0.z;
                vv[3] += cb0.w * expf(uf * la0.w) * P0.w;
                vv[4] += cb1.x * expf(uf * la1.x) * P1.x;
                vv[5] += cb1.y * expf(uf * la1.y) * P1.y;
                vv[6] += cb1.z * expf(uf * la1.z) * P1.z;
                vv[7] += cb1.w * expf(uf * la1.w) * P1.w;
            }
            u16 sh[8], sl[8];
#pragma unroll
            for (int j = 0; j < 8; ++j) split2(gelu_exact(vv[j]), sh[j], sl[j]);
            u16x8 vh = {sh[0], sh[1], sh[2], sh[3], sh[4], sh[5], sh[6], sh[7]};
            u16x8 vl = {sl[0], sl[1], sl[2], sl[3], sl[4], sl[5], sl[6], sl[7]};
            int aby = srow * 512 + ((u ^ (srow & 7)) << 4);
            *(u16x8*)(smem + AB_OFF + aby) = vh;
            *(u16x8*)(smem + AL_OFF + aby) = vl;
        }
        __syncthreads();   // bar A: Ah/Al (and hT at l==0) ready

        // ---- MFMA: A from LDS, B from packed global (L2-hot), depth-1 B prefetch ----
        f32x4 acc[2][4];
#pragma unroll
        for (int m = 0; m < 2; ++m)
#pragma unroll
            for (int n = 0; n < 4; ++n) acc[m][n] = (f32x4){0.f, 0.f, 0.f, 0.f};

        const u16* bhp = pWh + (size_t)l * 65536 + wn * 16384 + lane * 8;
        const u16* blp = pWl + (size_t)l * 65536 + wn * 16384 + lane * 8;

        V8 bhd[2][4], bld[2][4];
#pragma unroll
        for (int n = 0; n < 4; ++n) {
            bhd[0][n].u = *(const u16x8*)&bhp[n * 4096];
            bld[0][n].u = *(const u16x8*)&blp[n * 4096];
        }
#pragma unroll
        for (int ks = 0; ks < 8; ++ks) {
            int cur = ks & 1, nxt = cur ^ 1;
            if (ks < 7) {
#pragma unroll
                for (int n = 0; n < 4; ++n) {
                    bhd[nxt][n].u = *(const u16x8*)&bhp[n * 4096 + (ks + 1) * 512];
                    bld[nxt][n].u = *(const u16x8*)&blp[n * 4096 + (ks + 1) * 512];
                }
            }
            V8 ah[2], al[2];
#pragma unroll
            for (int m = 0; m < 2; ++m) {
                int row = wm * 32 + m * 16 + fr;
                int aby = row * 512 + (((ks * 4 + fq) ^ (row & 7)) << 4);
                ah[m].u = *(const u16x8*)(smem + AB_OFF + aby);
                al[m].u = *(const u16x8*)(smem + AL_OFF + aby);
            }
#pragma unroll
            for (int m = 0; m < 2; ++m)
#pragma unroll
                for (int n = 0; n < 4; ++n) {
                    acc[m][n] = __builtin_amdgcn_mfma_f32_16x16x32_bf16(ah[m].b, bhd[cur][n].b, acc[m][n], 0, 0, 0);
                    acc[m][n] = __builtin_amdgcn_mfma_f32_16x16x32_bf16(ah[m].b, bld[cur][n].b, acc[m][n], 0, 0, 0);
                    acc[m][n] = __builtin_amdgcn_mfma_f32_16x16x32_bf16(al[m].b, bhd[cur][n].b, acc[m][n], 0, 0, 0);
                }
        }

        // ---- epilogue p1: y = h + out2 + pb; row sums; cross-wave reduce ----
        if (l == 0) {
#pragma unroll
            for (int m = 0; m < 2; ++m)
#pragma unroll
                for (int n = 0; n < 4; ++n)
#pragma unroll
                    for (int r = 0; r < 4; ++r) {
                        int row = wm * 32 + m * 16 + fq * 4 + r;
                        int col = wn * 64 + n * 16 + fr;
                        hreg[m][n][r] = *(const float*)(smem + row * HT_STRIDE + col * 4);
                    }
        }
        float pbv[4], lgv[4], lbv[4];
#pragma unroll
        for (int n = 0; n < 4; ++n) {
            int col = wn * 64 + n * 16 + fr;
            pbv[n] = pb_all[l * DM + col];
            lgv[n] = lng_all[l * DM + col];
            lbv[n] = lnb_all[l * DM + col];
        }
        float s[2][4], ss[2][4];
#pragma unroll
        for (int m = 0; m < 2; ++m)
#pragma unroll
            for (int r = 0; r < 4; ++r) {
                float sy = 0.f, sy2 = 0.f;
#pragma unroll
                for (int n = 0; n < 4; ++n) {
                    float y = hreg[m][n][r] + acc[m][n][r] + pbv[n];
                    acc[m][n][r] = y;
                    sy += y; sy2 += y * y;
                }
                s[m][r] = sy; ss[m][r] = sy2;
            }
#pragma unroll
        for (int m = 0; m < 2; ++m)
#pragma unroll
            for (int r = 0; r < 4; ++r)
#pragma unroll
                for (int msk = 1; msk < 16; msk <<= 1) {
                    s[m][r]  += __shfl_xor(s[m][r],  msk);
                    ss[m][r] += __shfl_xor(ss[m][r], msk);
                }
        if (fr == 0) {
#pragma unroll
            for (int m = 0; m < 2; ++m)
#pragma unroll
                for (int r = 0; r < 4; ++r) {
                    int row = wm * 32 + m * 16 + fq * 4 + r;
                    *(float*)(smem + RED_OFF + (row * 8 + wn * 2)     * 4) = s[m][r];
                    *(float*)(smem + RED_OFF + (row * 8 + wn * 2 + 1) * 4) = ss[m][r];
                }
        }
        __syncthreads();   // bar B: red ready

        // ---- epilogue p2: LN, write-back, pooled, P_next ----
        float mean[2][4], rstd[2][4];
#pragma unroll
        for (int m = 0; m < 2; ++m)
#pragma unroll
            for (int r = 0; r < 4; ++r) {
                int row = wm * 32 + m * 16 + fq * 4 + r;
                float st = 0.f, sst = 0.f;
#pragma unroll
                for (int w = 0; w < 4; ++w) {
                    st  += *(const float*)(smem + RED_OFF + (row * 8 + w * 2)     * 4);
                    sst += *(const float*)(smem + RED_OFF + (row * 8 + w * 2 + 1) * 4);
                }
                float mu = st * (1.f / 256.f);
                float var = sst * (1.f / 256.f) - mu * mu;
                mean[m][r] = mu;
                rstd[m][r] = rsqrtf(var + LN_EPS);
            }
        int slot = (l == 1) ? 0 : (l == 3) ? 1 : (l == 5) ? 2 : (l == 7) ? 3 : -1;
        bool prod = (l < NLAYER - 1) && isProd;
        float lanv[4];
        if (prod) {
            const float* lan = logA_all + (l + 1) * DM;
#pragma unroll
            for (int n = 0; n < 4; ++n) lanv[n] = lan[wn * 64 + n * 16 + fr];
        }
        float cs[4] = {0.f, 0.f, 0.f, 0.f};
        float pc[4] = {0.f, 0.f, 0.f, 0.f};
#pragma unroll
        for (int m = 0; m < 2; ++m)
#pragma unroll
            for (int r = 0; r < 4; ++r) {
                int row  = wm * 32 + m * 16 + fq * 4 + r;
                int trow = blk * BM + row;
#pragma unroll
                for (int n = 0; n < 4; ++n) {
                    float o = (acc[m][n][r] - mean[m][r]) * rstd[m][r] * lgv[n] + lbv[n];
                    hreg[m][n][r] = o;
                    int col = wn * 64 + n * 16 + fr;
                    *(float*)(smem + row * HT_STRIDE + col * 4) = o;
                    if (slot >= 0) cs[n] += o;
                    if (prod && trow <= EMAX) pc[n] += o * expf((float)trow * lanv[n]);
                }
            }
        if (slot >= 0) {
#pragma unroll
            for (int n = 0; n < 4; ++n) {
                cs[n] += __shfl_xor(cs[n], 16);
                cs[n] += __shfl_xor(cs[n], 32);
            }
            if (lane < 16) {
#pragma unroll
                for (int n = 0; n < 4; ++n)
                    atomicAdd(&pooled[slot * (BATCH * DM) + b * DM + wn * 64 + n * 16 + lane], cs[n]);
            }
        }
        if (prod) {
#pragma unroll
            for (int n = 0; n < 4; ++n) {
                pc[n] += __shfl_xor(pc[n], 16);
                pc[n] += __shfl_xor(pc[n], 32);
            }
            if (lane < 16) {
#pragma unroll
                for (int n = 0; n < 4; ++n)
                    atomicAdd(&P_all[(size_t)(l + 1) * BATCH * DM + b * DM + wn * 64 + n * 16 + lane], pc[n]);
            }
        }
        __syncthreads();   // bar C: hT/red safe; all waves' P atomics drained
        if (prod && tid == 0)
            __hip_atomic_fetch_add(&flags[(l + 1) * BATCH + b], 1,
                                   __ATOMIC_RELEASE, __HIP_MEMORY_SCOPE_AGENT);
    }
}

// ---------------- head ----------------
__global__ void k_head(const float* __restrict__ pooled, const float* __restrict__ hW,
                       const float* __restrict__ hb, float* __restrict__ out) {
    int tid = threadIdx.x;
    if (tid >= 96) return;
    int e = tid / 24;
    int r = tid % 24;
    int b = r / 3;
    int n = r % 3;
    const float* pv = &pooled[e * (BATCH * DM) + b * DM];
    const float* wv = &hW[(e * 3 + n) * DM];
    float acc = 0.f;
    for (int c = 0; c < DM; ++c) acc += pv[c] * wv[c];
    out[e * 24 + b * 3 + n] = acc * (1.f / (float)LSEQ) + hb[e * 3 + n];
}

extern "C" void kernel_launch(void* const* d_in, const int* in_sizes, int n_in,
                              void* d_out, int out_size, void* d_ws, size_t ws_size,
                              hipStream_t stream) {
    const float* x   = (const float*)d_in[0];
    const float* inW = (const float*)d_in[1];
    const float* inb = (const float*)d_in[2];
    const float* Ap  = (const float*)d_in[3];
    const float* Bp  = (const float*)d_in[4];
    const float* Cp  = (const float*)d_in[5];
    const float* Dp  = (const float*)d_in[6];
    const float* pW  = (const float*)d_in[7];
    const float* pb  = (const float*)d_in[8];
    const float* lng = (const float*)d_in[9];
    const float* lnb = (const float*)d_in[10];
    const float* hW  = (const float*)d_in[11];
    const float* hb  = (const float*)d_in[12];
    float* out = (float*)d_out;

    float* ws = (float*)d_ws;
    float* P_all    = ws;                            // 8*8*256 = 16384
    float* logA_all = P_all + NLAYER * BATCH * DM;   // 2048
    float* CB_all   = logA_all + NLAYER * DM;        // 2048
    float* pooled   = CB_all + NLAYER * DM;          // 8192
    u16* pWh        = (u16*)(pooled + 4 * BATCH * DM);   // 524288 u16
    u16* pWl        = pWh + NLAYER * DM * DM;            // 524288 u16
    int* flags      = (int*)(pWl + NLAYER * DM * DM);    // 64 ints

    k_prepW<<<(NLAYER * DM * DM / 8) / 256, 256, 0, stream>>>(pW, pWh, pWl);
    k_prep0<<<BATCH, 256, 0, stream>>>(x, inW, inb, Ap, Bp, Cp,
                                       P_all, logA_all, CB_all, pooled, flags);
    k_fused<<<BATCH * 32, 512, 0, stream>>>(
        x, inW, inb, pWh, pWl, Dp, pb, lng, lnb,
        logA_all, CB_all, P_all, pooled, flags);
    k_head<<<1, 128, 0, stream>>>(pooled, hW, hb, out);
}

// Round 9
// 121.688 us; speedup vs baseline: 1.9258x; 1.1170x over previous
//
#include <hip/hip_runtime.h>
#include <math.h>

#define DM 256
#define LSEQ 2048
#define BATCH 8
#define NLAYER 8
#define EMAX 192
#define LN_EPS 1e-5f
#define BM 32
#define BLKS 64                     // blocks per batch
#define NPROD 7                     // producer blocks per batch (t<=192 in blk 0..6)
#define TAILB 57                    // first tail block (t>=1855)
#define ROWS (BATCH * LSEQ)

// LDS layout (bytes)
#define HT_STRIDE 1040              // 260 f32 per row
#define AB_OFF   33280              // 32*1040 -> Ah [32 rows][512 B, XOR-swizzled]
#define AL_OFF   (AB_OFF + 16384)   // Al
#define RED_OFF  (AL_OFF + 16384)   // red [32 rows][10] f32 (stride 10: conflict-free); aliases Pbuf
#define SMEM_SZ  (RED_OFF + 1280)   // 67328 B -> 2 blocks/CU

typedef float f32x4 __attribute__((ext_vector_type(4)));
typedef short bf16x8 __attribute__((ext_vector_type(8)));
typedef unsigned short u16;
typedef unsigned short u16x4 __attribute__((ext_vector_type(4)));
typedef unsigned short u16x8 __attribute__((ext_vector_type(8)));

union V8 { u16x8 u; bf16x8 b; };

// branch-free erf, Abramowitz-Stegun 7.1.26, |err| <= 1.5e-7
__device__ __forceinline__ float erf_fast(float x) {
    float ax = fabsf(x);
    float t = __builtin_amdgcn_rcpf(fmaf(0.3275911f, ax, 1.f));
    float p = fmaf(t, 1.061405429f, -1.453152027f);
    p = fmaf(t, p, 1.421413741f);
    p = fmaf(t, p, -0.284496736f);
    p = fmaf(t, p, 0.254829592f);
    p = p * t;
    float e = __expf(-ax * ax);
    float r = 1.f - p * e;
    return copysignf(r, x);
}

__device__ __forceinline__ float gelu_fast(float v) {
    return 0.5f * v * (1.f + erf_fast(v * 0.70710678118654752f));
}

// split fp32 -> bf16 hi (truncated, exact-subtractable) + bf16 lo (RNE of remainder)
__device__ __forceinline__ void split2(float g, u16& hi, u16& lo) {
    unsigned u = __float_as_uint(g);
    hi = (u16)(u >> 16);
    float fh = __uint_as_float(u & 0xFFFF0000u);
    float r = g - fh;
    unsigned v = __float_as_uint(r);
    v = v + 0x7FFFu + ((v >> 16) & 1u);
    lo = (u16)(v >> 16);
}

// ---------------- pre-split pW into MFMA-fragment-packed bf16 hi/lo ----------------
// packed[((cg*8+ks)*64+lane)*8 + j] = pW[col][k], col=(cg>>2)*64+(cg&3)*16+fr,
// k=ks*32+fq*8+j, lane=fq*16+fr.  (verified r5/r7/r8)
__global__ void k_prepW(const float* __restrict__ pW, u16* __restrict__ pWh,
                        u16* __restrict__ pWl) {
    int i = blockIdx.x * blockDim.x + threadIdx.x;
    int e = i * 8;
    int l = e >> 16;
    int r = e & 65535;
    int cg = r >> 12;
    int ks = (r >> 9) & 7;
    int lane = (r >> 3) & 63;
    int fq = lane >> 4, fr = lane & 15;
    int col = (cg >> 2) * 64 + (cg & 3) * 16 + fr;
    int k = ks * 32 + fq * 8;
    const float* src = pW + l * 65536 + col * 256 + k;
    float4 w0 = *(const float4*)src;
    float4 w1 = *(const float4*)(src + 4);
    float vv[8] = {w0.x, w0.y, w0.z, w0.w, w1.x, w1.y, w1.z, w1.w};
    u16 sh[8], sl[8];
#pragma unroll
    for (int j = 0; j < 8; ++j) split2(vv[j], sh[j], sl[j]);
    u16x8 vh = {sh[0], sh[1], sh[2], sh[3], sh[4], sh[5], sh[6], sh[7]};
    u16x8 vl = {sl[0], sl[1], sl[2], sl[3], sl[4], sl[5], sl[6], sl[7]};
    *(u16x8*)&pWh[e] = vh;
    *(u16x8*)&pWl[e] = vl;
}

// ---------------- prep0: logA/CB all layers, P[0], zero P[1..7] + pooled + flags ----------------
__global__ void k_prep0(const float* __restrict__ x, const float* __restrict__ inW,
                        const float* __restrict__ inb, const float* __restrict__ Ap,
                        const float* __restrict__ Bp, const float* __restrict__ Cp,
                        float* __restrict__ P_all, float* __restrict__ logA_all,
                        float* __restrict__ CB_all, float* __restrict__ pooled,
                        int* __restrict__ flags) {
    int b = blockIdx.x;
    int c = threadIdx.x;
    float A0 = 1.f / (1.f + expf(-Ap[c]));
    float iw = inW[c], ib = inb[c];
    const float* xb = x + b * LSEQ;
    float pw = 1.f, acc = 0.f;
    for (int t = 0; t <= EMAX; ++t) {
        acc += (xb[t] * iw + ib) * pw;
        pw *= A0;
    }
    P_all[b * DM + c] = acc;
    for (int l = 1; l < NLAYER; ++l) P_all[l * BATCH * DM + b * DM + c] = 0.f;
    for (int e = 0; e < 4; ++e) pooled[e * BATCH * DM + b * DM + c] = 0.f;
    if (b == 0) {
        for (int l = 0; l < NLAYER; ++l) {
            float Al = 1.f / (1.f + expf(-Ap[l * DM + c]));
            logA_all[l * DM + c] = logf(Al);
            CB_all[l * DM + c]   = Bp[l * DM + c] * Cp[l * DM + c];
        }
        if (c < NLAYER * BATCH) flags[c] = 0;
    }
}

// ---------------- persistent-tile fused kernel: 32 rows through all 8 layers ----------------
// Single launch, 512 blocks (2/CU, all co-resident), 256 thr = 4 waves (wave wn = col slice).
// Producer blocks (blk<=6) release flags[l+1][b]; tail blocks (blk>=57) spin + snapshot P.
__global__ __launch_bounds__(256, 2) void k_fused(
    const float* __restrict__ x, const float* __restrict__ inW,
    const float* __restrict__ inb,
    const u16* __restrict__ pWh, const u16* __restrict__ pWl,
    const float* __restrict__ Dp_all, const float* __restrict__ pb_all,
    const float* __restrict__ lng_all, const float* __restrict__ lnb_all,
    const float* __restrict__ logA_all, const float* __restrict__ CB_all,
    float* __restrict__ P_all, float* __restrict__ pooled,
    int* __restrict__ flags)
{
    __shared__ __align__(16) char smem[SMEM_SZ];

    int tid  = threadIdx.x;
    int lane = tid & 63;
    int wn   = tid >> 6;            // 0..3 col slice
    int fr   = lane & 15;
    int fq   = lane >> 4;

    int b    = blockIdx.x >> 6;
    int blk  = blockIdx.x & 63;
    int brow = b * LSEQ + blk * BM;
    bool isTail = (blk >= TAILB);
    bool isProd = (blk < NPROD);

    // stage map
    int srow = tid >> 3;                 // 0..31
    int gr_s = brow + srow;
    int t_s  = gr_s & (LSEQ - 1);
    int u_s  = (LSEQ - 1) - t_s;
    bool tail_s = (u_s <= EMAX);
    float uf = (float)u_s;
    float xv = x[gr_s];

    float hreg[2][4][4];                 // residual h for owned (m,n,r)
    float* Pbuf = (float*)(smem + RED_OFF);

    for (int l = 0; l < NLAYER; ++l) {
        const float* Dp  = Dp_all   + l * DM;
        const float* la  = logA_all + l * DM;
        const float* cbp = CB_all   + l * DM;

        // ---- tail blocks: wait for P[l] complete, snapshot into LDS ----
        if (isTail) {
            if (l >= 1 && tid == 0) {
                while (__hip_atomic_load(&flags[l * BATCH + b], __ATOMIC_ACQUIRE,
                                         __HIP_MEMORY_SCOPE_AGENT) < NPROD)
                    __builtin_amdgcn_s_sleep(2);
            }
            __syncthreads();
            if (tid < DM)
                Pbuf[tid] = __hip_atomic_load(
                    &P_all[(size_t)l * BATCH * DM + b * DM + tid],
                    __ATOMIC_RELAXED, __HIP_MEMORY_SCOPE_AGENT);
            __syncthreads();
        }

        // ---- early B prefetch (independent of stage) ----
        const u16* bhp = pWh + (size_t)l * 65536 + wn * 16384 + lane * 8;
        const u16* blp = pWl + (size_t)l * 65536 + wn * 16384 + lane * 8;
        V8 bhd[2][4], bld[2][4];
#pragma unroll
        for (int n = 0; n < 4; ++n) {
            bhd[0][n].u = *(const u16x8*)&bhp[n * 4096];
            bld[0][n].u = *(const u16x8*)&blp[n * 4096];
        }

        // ---- stage: g = split(gelu(D*h + tail)) into Ah/Al; l==0 also fills hT ----
#pragma unroll
        for (int i = 0; i < 4; ++i) {
            int u  = (tid & 7) + 8 * i;      // 16B chunk 0..31
            int kk = u * 8;
            int hby = srow * HT_STRIDE + u * 32;
            float hv[8];
            if (l == 0) {
                float4 w0 = *(const float4*)&inW[kk], w1 = *(const float4*)&inW[kk + 4];
                float4 b0 = *(const float4*)&inb[kk], b1 = *(const float4*)&inb[kk + 4];
                hv[0] = fmaf(xv, w0.x, b0.x); hv[1] = fmaf(xv, w0.y, b0.y);
                hv[2] = fmaf(xv, w0.z, b0.z); hv[3] = fmaf(xv, w0.w, b0.w);
                hv[4] = fmaf(xv, w1.x, b1.x); hv[5] = fmaf(xv, w1.y, b1.y);
                hv[6] = fmaf(xv, w1.z, b1.z); hv[7] = fmaf(xv, w1.w, b1.w);
                float4 o0 = {hv[0], hv[1], hv[2], hv[3]};
                float4 o1 = {hv[4], hv[5], hv[6], hv[7]};
                *(float4*)(smem + hby) = o0;
                *(float4*)(smem + hby + 16) = o1;
            } else {
                float4 h0 = *(const float4*)(smem + hby);
                float4 h1 = *(const float4*)(smem + hby + 16);
                hv[0] = h0.x; hv[1] = h0.y; hv[2] = h0.z; hv[3] = h0.w;
                hv[4] = h1.x; hv[5] = h1.y; hv[6] = h1.z; hv[7] = h1.w;
            }
            float4 d0 = *(const float4*)&Dp[kk];
            float4 d1 = *(const float4*)&Dp[kk + 4];
            float vv[8];
            vv[0] = hv[0] * d0.x; vv[1] = hv[1] * d0.y;
            vv[2] = hv[2] * d0.z; vv[3] = hv[3] * d0.w;
            vv[4] = hv[4] * d1.x; vv[5] = hv[5] * d1.y;
            vv[6] = hv[6] * d1.z; vv[7] = hv[7] * d1.w;
            if (tail_s) {
                float4 la0 = *(const float4*)&la[kk],  la1 = *(const float4*)&la[kk + 4];
                float4 cb0 = *(const float4*)&cbp[kk], cb1 = *(const float4*)&cbp[kk + 4];
                float4 P0  = *(const float4*)&Pbuf[kk], P1 = *(const float4*)&Pbuf[kk + 4];
                vv[0] += cb0.x * __expf(uf * la0.x) * P0.x;
                vv[1] += cb0.y * __expf(uf * la0.y) * P0.y;
                vv[2] += cb0.z * __expf(uf * la0.z) * P0.z;
                vv[3] += cb0.w * __expf(uf * la0.w) * P0.w;
                vv[4] += cb1.x * __expf(uf * la1.x) * P1.x;
                vv[5] += cb1.y * __expf(uf * la1.y) * P1.y;
                vv[6] += cb1.z * __expf(uf * la1.z) * P1.z;
                vv[7] += cb1.w * __expf(uf * la1.w) * P1.w;
            }
            u16 sh[8], sl[8];
#pragma unroll
            for (int j = 0; j < 8; ++j) split2(gelu_fast(vv[j]), sh[j], sl[j]);
            u16x8 vh = {sh[0], sh[1], sh[2], sh[3], sh[4], sh[5], sh[6], sh[7]};
            u16x8 vl = {sl[0], sl[1], sl[2], sl[3], sl[4], sl[5], sl[6], sl[7]};
            int aby = srow * 512 + ((u ^ (srow & 7)) << 4);
            *(u16x8*)(smem + AB_OFF + aby) = vh;
            *(u16x8*)(smem + AL_OFF + aby) = vl;
        }
        __syncthreads();   // bar A: Ah/Al (and hT at l==0) ready

        // ---- MFMA: A from LDS, B from packed global (L2-hot), depth-1 B prefetch ----
        f32x4 acc[2][4];
#pragma unroll
        for (int m = 0; m < 2; ++m)
#pragma unroll
            for (int n = 0; n < 4; ++n) acc[m][n] = (f32x4){0.f, 0.f, 0.f, 0.f};

#pragma unroll
        for (int ks = 0; ks < 8; ++ks) {
            int cur = ks & 1, nxt = cur ^ 1;
            if (ks < 7) {
#pragma unroll
                for (int n = 0; n < 4; ++n) {
                    bhd[nxt][n].u = *(const u16x8*)&bhp[n * 4096 + (ks + 1) * 512];
                    bld[nxt][n].u = *(const u16x8*)&blp[n * 4096 + (ks + 1) * 512];
                }
            }
            V8 ah[2], al[2];
#pragma unroll
            for (int m = 0; m < 2; ++m) {
                int row = m * 16 + fr;
                int aby = row * 512 + (((ks * 4 + fq) ^ (row & 7)) << 4);
                ah[m].u = *(const u16x8*)(smem + AB_OFF + aby);
                al[m].u = *(const u16x8*)(smem + AL_OFF + aby);
            }
#pragma unroll
            for (int m = 0; m < 2; ++m)
#pragma unroll
                for (int n = 0; n < 4; ++n) {
                    acc[m][n] = __builtin_amdgcn_mfma_f32_16x16x32_bf16(ah[m].b, bhd[cur][n].b, acc[m][n], 0, 0, 0);
                    acc[m][n] = __builtin_amdgcn_mfma_f32_16x16x32_bf16(ah[m].b, bld[cur][n].b, acc[m][n], 0, 0, 0);
                    acc[m][n] = __builtin_amdgcn_mfma_f32_16x16x32_bf16(al[m].b, bhd[cur][n].b, acc[m][n], 0, 0, 0);
                }
        }

        // ---- epilogue p1: y = h + out2 + pb; row sums; cross-wave reduce ----
        if (l == 0) {
#pragma unroll
            for (int m = 0; m < 2; ++m)
#pragma unroll
                for (int n = 0; n < 4; ++n)
#pragma unroll
                    for (int r = 0; r < 4; ++r) {
                        int row = m * 16 + fq * 4 + r;
                        int col = wn * 64 + n * 16 + fr;
                        hreg[m][n][r] = *(const float*)(smem + row * HT_STRIDE + col * 4);
                    }
        }
        float pbv[4], lgv[4], lbv[4];
#pragma unroll
        for (int n = 0; n < 4; ++n) {
            int col = wn * 64 + n * 16 + fr;
            pbv[n] = pb_all[l * DM + col];
            lgv[n] = lng_all[l * DM + col];
            lbv[n] = lnb_all[l * DM + col];
        }
        float s[2][4], ss[2][4];
#pragma unroll
        for (int m = 0; m < 2; ++m)
#pragma unroll
            for (int r = 0; r < 4; ++r) {
                float sy = 0.f, sy2 = 0.f;
#pragma unroll
                for (int n = 0; n < 4; ++n) {
                    float y = hreg[m][n][r] + acc[m][n][r] + pbv[n];
                    acc[m][n][r] = y;
                    sy += y; sy2 += y * y;
                }
                s[m][r] = sy; ss[m][r] = sy2;
            }
#pragma unroll
        for (int m = 0; m < 2; ++m)
#pragma unroll
            for (int r = 0; r < 4; ++r)
#pragma unroll
                for (int msk = 1; msk < 16; msk <<= 1) {
                    s[m][r]  += __shfl_xor(s[m][r],  msk);
                    ss[m][r] += __shfl_xor(ss[m][r], msk);
                }
        if (fr == 0) {
#pragma unroll
            for (int m = 0; m < 2; ++m)
#pragma unroll
                for (int r = 0; r < 4; ++r) {
                    int row = m * 16 + fq * 4 + r;
                    *(float*)(smem + RED_OFF + (row * 10 + wn * 2)     * 4) = s[m][r];
                    *(float*)(smem + RED_OFF + (row * 10 + wn * 2 + 1) * 4) = ss[m][r];
                }
        }
        __syncthreads();   // bar B: red ready

        // ---- epilogue p2: LN, write-back, pooled, P_next ----
        float mean[2][4], rstd[2][4];
#pragma unroll
        for (int m = 0; m < 2; ++m)
#pragma unroll
            for (int r = 0; r < 4; ++r) {
                int row = m * 16 + fq * 4 + r;
                float st = 0.f, sst = 0.f;
#pragma unroll
                for (int w = 0; w < 4; ++w) {
                    st  += *(const float*)(smem + RED_OFF + (row * 10 + w * 2)     * 4);
                    sst += *(const float*)(smem + RED_OFF + (row * 10 + w * 2 + 1) * 4);
                }
                float mu = st * (1.f / 256.f);
                float var = sst * (1.f / 256.f) - mu * mu;
                mean[m][r] = mu;
                rstd[m][r] = rsqrtf(var + LN_EPS);
            }
        int slot = (l == 1) ? 0 : (l == 3) ? 1 : (l == 5) ? 2 : (l == 7) ? 3 : -1;
        bool prod = (l < NLAYER - 1) && isProd;
        float lanv[4];
        if (prod) {
            const float* lan = logA_all + (l + 1) * DM;
#pragma unroll
            for (int n = 0; n < 4; ++n) lanv[n] = lan[wn * 64 + n * 16 + fr];
        }
        float cs[4] = {0.f, 0.f, 0.f, 0.f};
        float pc[4] = {0.f, 0.f, 0.f, 0.f};
#pragma unroll
        for (int m = 0; m < 2; ++m)
#pragma unroll
            for (int r = 0; r < 4; ++r) {
                int row  = m * 16 + fq * 4 + r;
                int trow = blk * BM + row;
#pragma unroll
                for (int n = 0; n < 4; ++n) {
                    float o = (acc[m][n][r] - mean[m][r]) * rstd[m][r] * lgv[n] + lbv[n];
                    hreg[m][n][r] = o;
                    int col = wn * 64 + n * 16 + fr;
                    *(float*)(smem + row * HT_STRIDE + col * 4) = o;
                    if (slot >= 0) cs[n] += o;
                    if (prod && trow <= EMAX) pc[n] += o * __expf((float)trow * lanv[n]);
                }
            }
        if (slot >= 0) {
#pragma unroll
            for (int n = 0; n < 4; ++n) {
                cs[n] += __shfl_xor(cs[n], 16);
                cs[n] += __shfl_xor(cs[n], 32);
            }
            if (lane < 16) {
#pragma unroll
                for (int n = 0; n < 4; ++n)
                    atomicAdd(&pooled[slot * (BATCH * DM) + b * DM + wn * 64 + n * 16 + lane], cs[n]);
            }
        }
        if (prod) {
#pragma unroll
            for (int n = 0; n < 4; ++n) {
                pc[n] += __shfl_xor(pc[n], 16);
                pc[n] += __shfl_xor(pc[n], 32);
            }
            if (lane < 16) {
#pragma unroll
                for (int n = 0; n < 4; ++n)
                    atomicAdd(&P_all[(size_t)(l + 1) * BATCH * DM + b * DM + wn * 64 + n * 16 + lane], pc[n]);
            }
        }
        __syncthreads();   // bar C: hT/red safe; all waves' P atomics drained
        if (prod && tid == 0)
            __hip_atomic_fetch_add(&flags[(l + 1) * BATCH + b], 1,
                                   __ATOMIC_RELEASE, __HIP_MEMORY_SCOPE_AGENT);
    }
}

// ---------------- head ----------------
__global__ void k_head(const float* __restrict__ pooled, const float* __restrict__ hW,
                       const float* __restrict__ hb, float* __restrict__ out) {
    int tid = threadIdx.x;
    if (tid >= 96) return;
    int e = tid / 24;
    int r = tid % 24;
    int b = r / 3;
    int n = r % 3;
    const float* pv = &pooled[e * (BATCH * DM) + b * DM];
    const float* wv = &hW[(e * 3 + n) * DM];
    float acc = 0.f;
    for (int c = 0; c < DM; ++c) acc += pv[c] * wv[c];
    out[e * 24 + b * 3 + n] = acc * (1.f / (float)LSEQ) + hb[e * 3 + n];
}

extern "C" void kernel_launch(void* const* d_in, const int* in_sizes, int n_in,
                              void* d_out, int out_size, void* d_ws, size_t ws_size,
                              hipStream_t stream) {
    const float* x   = (const float*)d_in[0];
    const float* inW = (const float*)d_in[1];
    const float* inb = (const float*)d_in[2];
    const float* Ap  = (const float*)d_in[3];
    const float* Bp  = (const float*)d_in[4];
    const float* Cp  = (const float*)d_in[5];
    const float* Dp  = (const float*)d_in[6];
    const float* pW  = (const float*)d_in[7];
    const float* pb  = (const float*)d_in[8];
    const float* lng = (const float*)d_in[9];
    const float* lnb = (const float*)d_in[10];
    const float* hW  = (const float*)d_in[11];
    const float* hb  = (const float*)d_in[12];
    float* out = (float*)d_out;

    float* ws = (float*)d_ws;
    float* P_all    = ws;                            // 8*8*256 = 16384
    float* logA_all = P_all + NLAYER * BATCH * DM;   // 2048
    float* CB_all   = logA_all + NLAYER * DM;        // 2048
    float* pooled   = CB_all + NLAYER * DM;          // 8192
    u16* pWh        = (u16*)(pooled + 4 * BATCH * DM);   // 524288 u16
    u16* pWl        = pWh + NLAYER * DM * DM;            // 524288 u16
    int* flags      = (int*)(pWl + NLAYER * DM * DM);    // 64 ints

    k_prepW<<<(NLAYER * DM * DM / 8) / 256, 256, 0, stream>>>(pW, pWh, pWl);
    k_prep0<<<BATCH, 256, 0, stream>>>(x, inW, inb, Ap, Bp, Cp,
                                       P_all, logA_all, CB_all, pooled, flags);
    k_fused<<<BATCH * BLKS, 256, 0, stream>>>(
        x, inW, inb, pWh, pWl, Dp, pb, lng, lnb,
        logA_all, CB_all, P_all, pooled, flags);
    k_head<<<1, 128, 0, stream>>>(pooled, hW, hb, out);
}